// Round 10
// baseline (124.326 us; speedup 1.0000x reference)
//
#include <hip/hip_runtime.h>

#define EPS 1e-10f

constexpr int B_ = 64, K_ = 4, M_ = 3, P_ = 65536;
constexpr int THREADS = 256;
constexpr int CH = 1024;                 // pixels per block
constexpr int NCH = P_ / CH;             // 64 chunks per b -> grid 4096
constexpr int NS = 32;                   // sums stride
constexpr int NACC = 29;                 // s0..3 t4..15 u16..27 n28

// Probe-shaped staging: 8 sequential phases; each phase = ONE contiguous
// plane slice, one float4 register load per thread, immediately ds_written.
// sched_barrier(0) between phases stops the compiler from re-batching all 8
// loads into the (slow) 8-concurrent-stream pattern. Phase order rotated per
// block to decorrelate the chip-wide sweep.
__device__ __forceinline__ void stage_phases(
    const float* __restrict__ pred, const float* __restrict__ inp,
    const int* __restrict__ heart, int b, int px0, int rot,
    float (*sbuf)[CH], int tid)
{
    #pragma unroll
    for (int ph = 0; ph < 8; ++ph) {
        const int pl = (ph + rot) & 7;
        const float* g;
        if (pl < 4)      g = pred + ((size_t)b * K_ + pl) * P_ + px0;
        else if (pl < 7) g = inp  + ((size_t)b * M_ + (pl - 4)) * P_ + px0;
        else             g = (const float*)(heart + (size_t)b * P_ + px0);
        const float4 v = ((const float4*)g)[tid];
        ((float4*)&sbuf[pl][0])[tid] = v;
        __builtin_amdgcn_sched_barrier(0);
    }
}

// ---- k_stats: per-(b,k) weighted sums + ROI count -------------------------
__global__ __launch_bounds__(THREADS) void k_stats(
    const float* __restrict__ pred, const float* __restrict__ inp,
    const int* __restrict__ heart, float* __restrict__ sums)
{
    __shared__ float sbuf[8][CH];        // 32 KB
    __shared__ float red[4][NACC];
    const int b     = blockIdx.x / NCH;
    const int chunk = blockIdx.x % NCH;
    const int tid   = threadIdx.x;

    stage_phases(pred, inp, heart, b, chunk * CH, blockIdx.x, sbuf, tid);
    __syncthreads();

    // each thread consumes exactly one float4 column from each plane
    const int4 h4 = ((const int4*)&sbuf[7][0])[tid];
    float4 pk[K_]; float4 xm[M_];
    #pragma unroll
    for (int k = 0; k < K_; ++k) pk[k] = ((const float4*)&sbuf[k][0])[tid];
    #pragma unroll
    for (int m = 0; m < M_; ++m) xm[m] = ((const float4*)&sbuf[4 + m][0])[tid];

    float sacc[K_], tacc[K_][M_], uacc[K_][M_], nacc = 0.f;
    #pragma unroll
    for (int k = 0; k < K_; ++k) {
        sacc[k] = 0.f;
        #pragma unroll
        for (int m = 0; m < M_; ++m) { tacc[k][m] = 0.f; uacc[k][m] = 0.f; }
    }

    #define PIX1(C) do {                                                      \
        const float w = (h4.C == 1) ? 1.f : 0.f;                              \
        nacc += w;                                                            \
        _Pragma("unroll")                                                     \
        for (int k = 0; k < K_; ++k) {                                        \
            const float pw = pk[k].C * w;                                     \
            sacc[k] += pw;                                                    \
            _Pragma("unroll")                                                 \
            for (int m = 0; m < M_; ++m) {                                    \
                const float x = xm[m].C;                                      \
                tacc[k][m] = fmaf(pw,     x, tacc[k][m]);                     \
                uacc[k][m] = fmaf(pw * x, x, uacc[k][m]);                     \
            }                                                                 \
        }                                                                     \
    } while (0)
    PIX1(x); PIX1(y); PIX1(z); PIX1(w);
    #undef PIX1

    float acc[NACC];
    #pragma unroll
    for (int k = 0; k < K_; ++k) {
        acc[k] = sacc[k];
        #pragma unroll
        for (int m = 0; m < M_; ++m) {
            acc[4  + k * M_ + m] = tacc[k][m];
            acc[16 + k * M_ + m] = uacc[k][m];
        }
    }
    acc[28] = nacc;

    const int lane = tid & 63, wid = tid >> 6;
    #pragma unroll
    for (int i = 0; i < NACC; ++i) {
        float x = acc[i];
        #pragma unroll
        for (int off = 32; off; off >>= 1) x += __shfl_down(x, off);
        if (lane == 0) red[wid][i] = x;
    }
    __syncthreads();
    if (tid < NACC) {
        const float x = red[0][tid] + red[1][tid] + red[2][tid] + red[3][tid];
        atomicAdd(&sums[b * NS + tid], x);
    }
}

// ---- k_loss: inline derivation + mixture log-likelihood -------------------
__global__ __launch_bounds__(THREADS) void k_loss(
    const float* __restrict__ pred, const float* __restrict__ inp,
    const int* __restrict__ heart, const float* __restrict__ sums,
    float* __restrict__ out)
{
    __shared__ float sbuf[8][CH];        // 32 KB
    __shared__ float red[4];
    const int b     = blockIdx.x / NCH;
    const int chunk = blockIdx.x % NCH;
    const int tid   = threadIdx.x;

    // derivation from 29 broadcast sums (overlaps staging)
    const float* sb = sums + b * NS;
    float mu[K_][M_], iv[K_][M_], ck[K_];
    #pragma unroll
    for (int k = 0; k < K_; ++k) {
        const float s = sb[k] + EPS;
        const float inv_s = 1.f / s;
        float c = 1.f;
        #pragma unroll
        for (int m = 0; m < M_; ++m) {
            const float t = sb[4  + k * M_ + m];
            const float u = sb[16 + k * M_ + m];
            const float muv = t * inv_s;
            const float var = fmaf(-muv, muv, u * inv_s) + EPS;
            mu[k][m] = muv;
            iv[k][m] = 0.5f / var;
            c *= rsqrtf(6.283185307179586f * var);
        }
        ck[k] = c;
    }
    const float invn = 1.f / (sb[28] * (float)B_);

    stage_phases(pred, inp, heart, b, chunk * CH, blockIdx.x, sbuf, tid);
    __syncthreads();

    const int4 h4 = ((const int4*)&sbuf[7][0])[tid];
    float4 pk[K_]; float4 xm[M_];
    #pragma unroll
    for (int k = 0; k < K_; ++k) pk[k] = ((const float4*)&sbuf[k][0])[tid];
    #pragma unroll
    for (int m = 0; m < M_; ++m) xm[m] = ((const float4*)&sbuf[4 + m][0])[tid];

    float part = 0.f;
    #define PIX3(C) do {                                                      \
        const float w = (h4.C == 1) ? 1.f : 0.f;                              \
        float mix = EPS;                                                      \
        _Pragma("unroll")                                                     \
        for (int k = 0; k < K_; ++k) {                                        \
            float e = 0.f;                                                    \
            _Pragma("unroll")                                                 \
            for (int m = 0; m < M_; ++m) {                                    \
                const float d = xm[m].C - mu[k][m];                           \
                e = fmaf(-(d * d), iv[k][m], e);                              \
            }                                                                 \
            mix = fmaf(pk[k].C * ck[k], __expf(e), mix);                      \
        }                                                                     \
        part = fmaf(w, __logf(mix), part);                                    \
    } while (0)
    PIX3(x); PIX3(y); PIX3(z); PIX3(w);
    #undef PIX3

    const int lane = tid & 63, wid = tid >> 6;
    float x = part;
    #pragma unroll
    for (int off = 32; off; off >>= 1) x += __shfl_down(x, off);
    if (lane == 0) red[wid] = x;
    __syncthreads();
    if (tid == 0)
        atomicAdd(out, -(red[0] + red[1] + red[2] + red[3]) * invn);
}

extern "C" void kernel_launch(void* const* d_in, const int* in_sizes, int n_in,
                              void* d_out, int out_size, void* d_ws, size_t ws_size,
                              hipStream_t stream)
{
    const float* pred  = (const float*)d_in[0];
    const float* inp   = (const float*)d_in[1];
    const int*   heart = (const int*)d_in[2];
    float* out  = (float*)d_out;
    float* sums = (float*)d_ws;            // B*32 floats

    hipMemsetAsync(sums, 0, B_ * NS * sizeof(float), stream);
    hipMemsetAsync(out,  0, sizeof(float), stream);

    k_stats<<<B_ * NCH, THREADS, 0, stream>>>(pred, inp, heart, sums);
    k_loss <<<B_ * NCH, THREADS, 0, stream>>>(pred, inp, heart, sums, out);
}

// Round 12
// 72.881 us; speedup vs baseline: 1.7059x; 1.7059x over previous
//
#include <hip/hip_runtime.h>

#define EPS 1e-10f

constexpr int B_ = 64, K_ = 4, M_ = 3, P_ = 65536;
constexpr int THREADS = 256;
constexpr int CHUNK = 2048;                 // pixels per block
constexpr int BPB = P_ / CHUNK;             // 32 -> 2048 blocks
constexpr int NS = 32;                      // sums stride
constexpr int NACC = 29;                    // s0..3 t4..15 u16..27 n28

// One asm block = 8 simultaneous global_load_dwordx4 (early-clobber outputs
// force 8-wide issue; the compiler cannot serialize within an asm block).
#define LOAD8(P0,P1,P2,P3,X0,X1,X2,H, A0,A1,A2,A3,A4,A5,A6,A7)                \
    asm volatile(                                                             \
        "global_load_dwordx4 %0, %8, off\n\t"                                 \
        "global_load_dwordx4 %1, %9, off\n\t"                                 \
        "global_load_dwordx4 %2, %10, off\n\t"                                \
        "global_load_dwordx4 %3, %11, off\n\t"                                \
        "global_load_dwordx4 %4, %12, off\n\t"                                \
        "global_load_dwordx4 %5, %13, off\n\t"                                \
        "global_load_dwordx4 %6, %14, off\n\t"                                \
        "global_load_dwordx4 %7, %15, off"                                    \
        : "=&v"(P0), "=&v"(P1), "=&v"(P2), "=&v"(P3),                         \
          "=&v"(X0), "=&v"(X1), "=&v"(X2), "=&v"(H)                           \
        : "v"(A0), "v"(A1), "v"(A2), "v"(A3),                                 \
          "v"(A4), "v"(A5), "v"(A6), "v"(A7))

// Counted wait + sched_barrier fence (rule #18: the barrier stops hipcc from
// hoisting register-only consumption above the waitcnt).
#define WAITV(N) do {                                                         \
    asm volatile("s_waitcnt vmcnt(" #N ")" ::: "memory");                     \
    __builtin_amdgcn_sched_barrier(0);                                        \
} while (0)

// ---- k_stats: per-(b,k) weighted sums + ROI count -------------------------
__global__ __launch_bounds__(THREADS, 3) void k_stats(
    const float* __restrict__ pred, const float* __restrict__ inp,
    const int* __restrict__ heart, float* __restrict__ sums)
{
    const int b     = blockIdx.x / BPB;
    const int chunk = blockIdx.x % BPB;
    const int tid   = threadIdx.x;
    const int v0    = chunk * (CHUNK / 4) + tid;     // float4 index, iter 0

    const float4* ap0 = (const float4*)(pred + ((size_t)b * K_ + 0) * P_) + v0;
    const float4* ap1 = (const float4*)(pred + ((size_t)b * K_ + 1) * P_) + v0;
    const float4* ap2 = (const float4*)(pred + ((size_t)b * K_ + 2) * P_) + v0;
    const float4* ap3 = (const float4*)(pred + ((size_t)b * K_ + 3) * P_) + v0;
    const float4* ax0 = (const float4*)(inp  + ((size_t)b * M_ + 0) * P_) + v0;
    const float4* ax1 = (const float4*)(inp  + ((size_t)b * M_ + 1) * P_) + v0;
    const float4* ax2 = (const float4*)(inp  + ((size_t)b * M_ + 2) * P_) + v0;
    const int4*   ah  = (const int4*)(heart + (size_t)b * P_) + v0;

    float4 pa0, pa1, pa2, pa3, xa0, xa1, xa2; int4 ha;
    float4 pb0, pb1, pb2, pb3, xb0, xb1, xb2; int4 hb;

    LOAD8(pa0,pa1,pa2,pa3,xa0,xa1,xa2,ha, ap0,ap1,ap2,ap3,ax0,ax1,ax2,ah);
    LOAD8(pb0,pb1,pb2,pb3,xb0,xb1,xb2,hb,
          ap0+256,ap1+256,ap2+256,ap3+256,ax0+256,ax1+256,ax2+256,ah+256);

    // accumulator init overlaps the load flight (register-only, vmcnt-safe)
    float sacc[K_], tacc[K_][M_], uacc[K_][M_], nacc = 0.f;
    #pragma unroll
    for (int k = 0; k < K_; ++k) {
        sacc[k] = 0.f;
        #pragma unroll
        for (int m = 0; m < M_; ++m) { tacc[k][m] = 0.f; uacc[k][m] = 0.f; }
    }

    #define CONSUME1(PK0,PK1,PK2,PK3,XM0,XM1,XM2,H4,C) do {                   \
        const float w = (H4.C == 1) ? 1.f : 0.f;                              \
        nacc += w;                                                            \
        const float pw0 = PK0.C * w, pw1 = PK1.C * w;                         \
        const float pw2 = PK2.C * w, pw3 = PK3.C * w;                         \
        sacc[0] += pw0; sacc[1] += pw1; sacc[2] += pw2; sacc[3] += pw3;       \
        const float x0 = XM0.C, x1 = XM1.C, x2 = XM2.C;                       \
        tacc[0][0] = fmaf(pw0, x0, tacc[0][0]);                               \
        tacc[0][1] = fmaf(pw0, x1, tacc[0][1]);                               \
        tacc[0][2] = fmaf(pw0, x2, tacc[0][2]);                               \
        tacc[1][0] = fmaf(pw1, x0, tacc[1][0]);                               \
        tacc[1][1] = fmaf(pw1, x1, tacc[1][1]);                               \
        tacc[1][2] = fmaf(pw1, x2, tacc[1][2]);                               \
        tacc[2][0] = fmaf(pw2, x0, tacc[2][0]);                               \
        tacc[2][1] = fmaf(pw2, x1, tacc[2][1]);                               \
        tacc[2][2] = fmaf(pw2, x2, tacc[2][2]);                               \
        tacc[3][0] = fmaf(pw3, x0, tacc[3][0]);                               \
        tacc[3][1] = fmaf(pw3, x1, tacc[3][1]);                               \
        tacc[3][2] = fmaf(pw3, x2, tacc[3][2]);                               \
        uacc[0][0] = fmaf(pw0 * x0, x0, uacc[0][0]);                          \
        uacc[0][1] = fmaf(pw0 * x1, x1, uacc[0][1]);                          \
        uacc[0][2] = fmaf(pw0 * x2, x2, uacc[0][2]);                          \
        uacc[1][0] = fmaf(pw1 * x0, x0, uacc[1][0]);                          \
        uacc[1][1] = fmaf(pw1 * x1, x1, uacc[1][1]);                          \
        uacc[1][2] = fmaf(pw1 * x2, x2, uacc[1][2]);                          \
        uacc[2][0] = fmaf(pw2 * x0, x0, uacc[2][0]);                          \
        uacc[2][1] = fmaf(pw2 * x1, x1, uacc[2][1]);                          \
        uacc[2][2] = fmaf(pw2 * x2, x2, uacc[2][2]);                          \
        uacc[3][0] = fmaf(pw3 * x0, x0, uacc[3][0]);                          \
        uacc[3][1] = fmaf(pw3 * x1, x1, uacc[3][1]);                          \
        uacc[3][2] = fmaf(pw3 * x2, x2, uacc[3][2]);                          \
    } while (0)

    WAITV(8);
    CONSUME1(pa0,pa1,pa2,pa3,xa0,xa1,xa2,ha, x);
    CONSUME1(pa0,pa1,pa2,pa3,xa0,xa1,xa2,ha, y);
    CONSUME1(pa0,pa1,pa2,pa3,xa0,xa1,xa2,ha, z);
    CONSUME1(pa0,pa1,pa2,pa3,xa0,xa1,xa2,ha, w);
    WAITV(0);
    CONSUME1(pb0,pb1,pb2,pb3,xb0,xb1,xb2,hb, x);
    CONSUME1(pb0,pb1,pb2,pb3,xb0,xb1,xb2,hb, y);
    CONSUME1(pb0,pb1,pb2,pb3,xb0,xb1,xb2,hb, z);
    CONSUME1(pb0,pb1,pb2,pb3,xb0,xb1,xb2,hb, w);
    #undef CONSUME1

    float acc[NACC];
    #pragma unroll
    for (int k = 0; k < K_; ++k) {
        acc[k] = sacc[k];
        #pragma unroll
        for (int m = 0; m < M_; ++m) {
            acc[4  + k * M_ + m] = tacc[k][m];
            acc[16 + k * M_ + m] = uacc[k][m];
        }
    }
    acc[28] = nacc;

    __shared__ float red[4][NACC];
    const int lane = tid & 63, wid = tid >> 6;
    #pragma unroll
    for (int i = 0; i < NACC; ++i) {
        float x = acc[i];
        #pragma unroll
        for (int off = 32; off; off >>= 1) x += __shfl_down(x, off);
        if (lane == 0) red[wid][i] = x;
    }
    __syncthreads();
    if (tid < NACC) {
        const float x = red[0][tid] + red[1][tid] + red[2][tid] + red[3][tid];
        atomicAdd(&sums[b * NS + tid], x);
    }
}

// ---- k_loss: inline derivation + mixture log-likelihood -------------------
__global__ __launch_bounds__(THREADS, 3) void k_loss(
    const float* __restrict__ pred, const float* __restrict__ inp,
    const int* __restrict__ heart, const float* __restrict__ sums,
    float* __restrict__ out)
{
    const int b     = blockIdx.x / BPB;
    const int chunk = blockIdx.x % BPB;
    const int tid   = threadIdx.x;
    const int v0    = chunk * (CHUNK / 4) + tid;

    // derivation FIRST: its loads must not sit between the asm loads and the
    // counted vmcnt (vmcnt decrements in issue order).
    const float* sb = sums + b * NS;
    float mu[K_][M_], iv[K_][M_], ck[K_];
    #pragma unroll
    for (int k = 0; k < K_; ++k) {
        const float s = sb[k] + EPS;
        const float inv_s = 1.f / s;
        float c = 1.f;
        #pragma unroll
        for (int m = 0; m < M_; ++m) {
            const float t = sb[4  + k * M_ + m];
            const float u = sb[16 + k * M_ + m];
            const float muv = t * inv_s;
            const float var = fmaf(-muv, muv, u * inv_s) + EPS;
            mu[k][m] = muv;
            iv[k][m] = 0.5f / var;
            c *= rsqrtf(6.283185307179586f * var);
        }
        ck[k] = c;
    }
    const float invn = 1.f / (sb[28] * (float)B_);
    __builtin_amdgcn_sched_barrier(0);     // keep derivation loads above LOAD8

    const float4* ap0 = (const float4*)(pred + ((size_t)b * K_ + 0) * P_) + v0;
    const float4* ap1 = (const float4*)(pred + ((size_t)b * K_ + 1) * P_) + v0;
    const float4* ap2 = (const float4*)(pred + ((size_t)b * K_ + 2) * P_) + v0;
    const float4* ap3 = (const float4*)(pred + ((size_t)b * K_ + 3) * P_) + v0;
    const float4* ax0 = (const float4*)(inp  + ((size_t)b * M_ + 0) * P_) + v0;
    const float4* ax1 = (const float4*)(inp  + ((size_t)b * M_ + 1) * P_) + v0;
    const float4* ax2 = (const float4*)(inp  + ((size_t)b * M_ + 2) * P_) + v0;
    const int4*   ah  = (const int4*)(heart + (size_t)b * P_) + v0;

    float4 pa0, pa1, pa2, pa3, xa0, xa1, xa2; int4 ha;
    float4 pb0, pb1, pb2, pb3, xb0, xb1, xb2; int4 hb;

    LOAD8(pa0,pa1,pa2,pa3,xa0,xa1,xa2,ha, ap0,ap1,ap2,ap3,ax0,ax1,ax2,ah);
    LOAD8(pb0,pb1,pb2,pb3,xb0,xb1,xb2,hb,
          ap0+256,ap1+256,ap2+256,ap3+256,ax0+256,ax1+256,ax2+256,ah+256);

    float part = 0.f;
    #define CONSUME3(PK0,PK1,PK2,PK3,XM0,XM1,XM2,H4,C) do {                   \
        const float w = (H4.C == 1) ? 1.f : 0.f;                              \
        const float x0 = XM0.C, x1 = XM1.C, x2 = XM2.C;                       \
        float mix = EPS;                                                      \
        {                                                                     \
            const float d0 = x0 - mu[0][0], d1 = x1 - mu[0][1], d2 = x2 - mu[0][2]; \
            float e = -(d0 * d0) * iv[0][0];                                  \
            e = fmaf(-(d1 * d1), iv[0][1], e);                                \
            e = fmaf(-(d2 * d2), iv[0][2], e);                                \
            mix = fmaf(PK0.C * ck[0], __expf(e), mix);                        \
        }{                                                                    \
            const float d0 = x0 - mu[1][0], d1 = x1 - mu[1][1], d2 = x2 - mu[1][2]; \
            float e = -(d0 * d0) * iv[1][0];                                  \
            e = fmaf(-(d1 * d1), iv[1][1], e);                                \
            e = fmaf(-(d2 * d2), iv[1][2], e);                                \
            mix = fmaf(PK1.C * ck[1], __expf(e), mix);                        \
        }{                                                                    \
            const float d0 = x0 - mu[2][0], d1 = x1 - mu[2][1], d2 = x2 - mu[2][2]; \
            float e = -(d0 * d0) * iv[2][0];                                  \
            e = fmaf(-(d1 * d1), iv[2][1], e);                                \
            e = fmaf(-(d2 * d2), iv[2][2], e);                                \
            mix = fmaf(PK2.C * ck[2], __expf(e), mix);                        \
        }{                                                                    \
            const float d0 = x0 - mu[3][0], d1 = x1 - mu[3][1], d2 = x2 - mu[3][2]; \
            float e = -(d0 * d0) * iv[3][0];                                  \
            e = fmaf(-(d1 * d1), iv[3][1], e);                                \
            e = fmaf(-(d2 * d2), iv[3][2], e);                                \
            mix = fmaf(PK3.C * ck[3], __expf(e), mix);                        \
        }                                                                     \
        part = fmaf(w, __logf(mix), part);                                    \
    } while (0)

    WAITV(8);
    CONSUME3(pa0,pa1,pa2,pa3,xa0,xa1,xa2,ha, x);
    CONSUME3(pa0,pa1,pa2,pa3,xa0,xa1,xa2,ha, y);
    CONSUME3(pa0,pa1,pa2,pa3,xa0,xa1,xa2,ha, z);
    CONSUME3(pa0,pa1,pa2,pa3,xa0,xa1,xa2,ha, w);
    WAITV(0);
    CONSUME3(pb0,pb1,pb2,pb3,xb0,xb1,xb2,hb, x);
    CONSUME3(pb0,pb1,pb2,pb3,xb0,xb1,xb2,hb, y);
    CONSUME3(pb0,pb1,pb2,pb3,xb0,xb1,xb2,hb, z);
    CONSUME3(pb0,pb1,pb2,pb3,xb0,xb1,xb2,hb, w);
    #undef CONSUME3

    __shared__ float red[4];
    const int lane = tid & 63, wid = tid >> 6;
    float x = part;
    #pragma unroll
    for (int off = 32; off; off >>= 1) x += __shfl_down(x, off);
    if (lane == 0) red[wid] = x;
    __syncthreads();
    if (tid == 0)
        atomicAdd(out, -(red[0] + red[1] + red[2] + red[3]) * invn);
}

extern "C" void kernel_launch(void* const* d_in, const int* in_sizes, int n_in,
                              void* d_out, int out_size, void* d_ws, size_t ws_size,
                              hipStream_t stream)
{
    const float* pred  = (const float*)d_in[0];
    const float* inp   = (const float*)d_in[1];
    const int*   heart = (const int*)d_in[2];
    float* out  = (float*)d_out;
    float* sums = (float*)d_ws;            // B*32 floats

    hipMemsetAsync(sums, 0, B_ * NS * sizeof(float), stream);
    hipMemsetAsync(out,  0, sizeof(float), stream);

    k_stats<<<B_ * BPB, THREADS, 0, stream>>>(pred, inp, heart, sums);
    k_loss <<<B_ * BPB, THREADS, 0, stream>>>(pred, inp, heart, sums, out);
}